// Round 3
// baseline (138.834 us; speedup 1.0000x reference)
//
#include <hip/hip_runtime.h>
#include <hip/hip_bf16.h>
#include <stdint.h>

// Problem constants
#define M_TOK 16384   // B*S = 8*2048
#define E_DIM 768
#define FF_DIM 3072
#define Q_N 8

typedef __attribute__((ext_vector_type(8))) short bf16x8;
typedef __attribute__((ext_vector_type(4))) float f32x4;

__device__ inline unsigned short f2bf(float f) {
  union { float f; unsigned u; } v; v.f = f;
  unsigned r = v.u + 0x7fffu + ((v.u >> 16) & 1u);  // round-to-nearest-even
  return (unsigned short)(r >> 16);
}

// ---------------- kernel 0: w2 fp32 -> bf16 ----------------
__global__ __launch_bounds__(256) void cvt_w2(const float* __restrict__ w2,
                                              __hip_bfloat16* __restrict__ w2b) {
  int i = (blockIdx.x * 256 + threadIdx.x) * 4;
  const int n = E_DIM * FF_DIM;
  if (i < n) {
    float4 v = *(const float4*)(w2 + i);
    ushort4 o;
    o.x = f2bf(v.x); o.y = f2bf(v.y); o.z = f2bf(v.z); o.w = f2bf(v.w);
    *(ushort4*)((unsigned short*)w2b + i) = o;
  }
}

// ---------------- fused kernel: C = relu(cos(x+phi)@w1^T+b1) @ w2b^T + b2 ---
// R3: compute_h ELIMINATED. The GEMM block produces its own A-tile:
//   h[row][f] for (row = m0+s*64+rs, f = K0+lc*8+j) is computed by exactly the
//   thread that used to GLDS16-stage those bytes, with bit-identical math
//   (f32 meas/fma in compute_h's order, same f2bf), then ds_write_b128 to the
//   SAME swizzled LDS addresses. B-path/frags/MFMA/epilogue unchanged.
//   w1 K-slice (2KB/tile) staged 2 tiles ahead via GLDS16 (waves 0-1 only;
//   tile-end vmcnt(0) tolerates per-wave count asymmetry) with XOR source
//   swizzle so per-thread wq reads are bank-conflict-free. b1 reg-staged
//   2 ahead. meas (256x8 f32) computed once into LDS, then held in 32 VGPR.
#define GLDS16(g, l)                                                          \
  __builtin_amdgcn_global_load_lds(                                           \
      (const __attribute__((address_space(1))) void*)(g),                     \
      (__attribute__((address_space(3))) void*)(l), 16, 0, 0)

#define BUF_ELEMS 28672   // (256*64 + 192*64) bf16 elems = 56KB
#define B_OFF 16384       // A region: 256*64 elems

__global__ __launch_bounds__(512, 1) void ffn_fused(const float* __restrict__ x,
                                                    const float* __restrict__ phi,
                                                    const float* __restrict__ w1,
                                                    const float* __restrict__ b1,
                                                    const __hip_bfloat16* __restrict__ Bw,
                                                    const float* __restrict__ b2,
                                                    float* __restrict__ C) {
  const int K = FF_DIM;   // 3072
  const int N = E_DIM;    // 768

  __shared__ __align__(16) __hip_bfloat16 lds[2 * BUF_ELEMS];  // 112 KiB
  __shared__ __align__(16) float s_meas[256][8];               // 8 KiB
  __shared__ __align__(16) float w1s[2][512];                  // 4 KiB (2KB/slice)

  const int t = threadIdx.x;
  // XCD-aware bijective swizzle: nwg = 256, 256 % 8 == 0
  const int swz = (blockIdx.x & 7) * 32 + (blockIdx.x >> 3);
  const int bm = swz >> 2;        // 0..63
  const int bn = swz & 3;         // 0..3
  const size_t m0 = (size_t)bm * 256;
  const int n0 = bn * 192;

  const int w = t >> 6, l = t & 63;
  const int wr = w >> 2;          // 0..1  (M wave row)
  const int wc = w & 3;           // 0..3  (N wave col)
  const int lr = l & 15;
  const int lk = l >> 4;          // 0..3

  // fragment-read swizzled chunk constants
  const int x0 = lk ^ (lr & 7);
  const int x1 = x0 ^ 4;
  const int baseA = (wr * 128 + lr) * 64;
  const int baseB = B_OFF + (wc * 48 + lr) * 64;
  const int offA0 = baseA + x0 * 8, offA1 = baseA + x1 * 8;
  const int offB0 = baseB + x0 * 8, offB1 = baseB + x1 * 8;

  // staging geometry: rs = row-in-span, lc = logical 8-elem chunk (XOR swizzle)
  const int rs = t >> 3;
  const int lc = (t & 7) ^ (rs & 7);
  const __hip_bfloat16* sB[3];
#pragma unroll
  for (int s = 0; s < 3; ++s) sB[s] = Bw + ((size_t)n0 + s * 64 + rs) * K + lc * 8;

  // w1 staging source map (threads 0..127): phys chunk p=t holds logical
  // chunk c = (p>>4)*16 + ((p&15)^((p>>4)&7)); src float offset = c*4.
  const int c4 = (((t >> 4) << 4) + ((t & 15) ^ ((t >> 4) & 7))) * 4;

  f32x4 acc[8][3] = {};

  // ---- prologue: meas = cos(x[:, :8] + phi), bit-identical to compute_h ----
  {
    const int m = t >> 1, hh = t & 1;
    float4 v = *(const float4*)(x + (m0 + m) * (size_t)E_DIM + hh * 4);
    float4 p = *(const float4*)(phi + hh * 4);
    f32x4 cv;
    cv[0] = __cosf(v.x + p.x); cv[1] = __cosf(v.y + p.y);
    cv[2] = __cosf(v.z + p.z); cv[3] = __cosf(v.w + p.w);
    *(f32x4*)&s_meas[m][hh * 4] = cv;
  }
  asm volatile("s_waitcnt lgkmcnt(0)" ::: "memory");
  __builtin_amdgcn_s_barrier();

  // per-thread meas rows (fixed across all K-tiles) -> 32 VGPR
  float mv[4][8];
#pragma unroll
  for (int s = 0; s < 4; ++s) {
    f32x4 a = *(const f32x4*)&s_meas[rs + 64 * s][0];
    f32x4 b = *(const f32x4*)&s_meas[rs + 64 * s][4];
    mv[s][0] = a[0]; mv[s][1] = a[1]; mv[s][2] = a[2]; mv[s][3] = a[3];
    mv[s][4] = b[0]; mv[s][5] = b[1]; mv[s][6] = b[2]; mv[s][7] = b[3];
  }

  // stage w1 slice 0 and 1 (waves 0-1 only; wave-uniform branch)
  if (t < 128) {
    GLDS16(w1 + c4, (float*)w1s[0] + t * 4);
    GLDS16(w1 + 512 + c4, (float*)w1s[1] + t * 4);
  }
  f32x4 b1a = *(const f32x4*)(b1 + lc * 8);
  f32x4 b1b = *(const f32x4*)(b1 + lc * 8 + 4);

  asm volatile("s_waitcnt vmcnt(0) lgkmcnt(0)" ::: "memory");
  __builtin_amdgcn_s_barrier();

  // h-compute: produce A-tile K-slice into Abuf[WBUF] using w1s[WSEL] + b1a/b1b
#define HCOMP(WSEL, WBUF)                                                     \
  {                                                                           \
    const float* wbuf = w1s[(WSEL)];                                          \
    __hip_bfloat16* ldh = lds + (WBUF) * BUF_ELEMS + t * 8;                   \
    f32x4 wq[16];                                                             \
    _Pragma("unroll") for (int jj = 0; jj < 16; ++jj)                         \
        wq[jj] = *(const f32x4*)(wbuf + (lc * 16 + (jj ^ lc)) * 4);           \
    _Pragma("unroll") for (int s = 0; s < 4; ++s) {                           \
      uint32_t pk[4];                                                         \
      _Pragma("unroll") for (int j = 0; j < 8; ++j) {                         \
        float a = (j < 4) ? b1a[j] : b1b[j - 4];                              \
        _Pragma("unroll") for (int q = 0; q < 8; ++q)                         \
            a = fmaf(mv[s][q], wq[j * 2 + (q >> 2)][q & 3], a);               \
        a = fmaxf(a, 0.f);                                                    \
        unsigned short u = f2bf(a);                                           \
        if (j & 1) pk[j >> 1] |= ((uint32_t)u) << 16;                         \
        else pk[j >> 1] = (uint32_t)u;                                        \
      }                                                                       \
      uint4 pv; pv.x = pk[0]; pv.y = pk[1]; pv.z = pk[2]; pv.w = pk[3];       \
      *(uint4*)(ldh + s * 4096) = pv;                                         \
    }                                                                         \
  }

#define STAGE_B(K0S, WBUF)                                                    \
  {                                                                           \
    __hip_bfloat16* ld = lds + (WBUF) * BUF_ELEMS + t * 8;                    \
    GLDS16(sB[0] + (K0S), ld + 16384);                                        \
    GLDS16(sB[1] + (K0S), ld + 20480);                                        \
    GLDS16(sB[2] + (K0S), ld + 24576);                                        \
  }

  // prologue: A(0) computed, B(0) staged
  HCOMP(0, 0);
  b1a = *(const f32x4*)(b1 + 64 + lc * 8);
  b1b = *(const f32x4*)(b1 + 64 + lc * 8 + 4);
  STAGE_B(0, 0);
  asm volatile("s_waitcnt vmcnt(0) lgkmcnt(0)" ::: "memory");
  __builtin_amdgcn_s_barrier();

#define TILE(KT, RBUF, DO_AB, DO_W1)                                          \
  {                                                                           \
    const __hip_bfloat16* la = lds + (RBUF) * BUF_ELEMS;                      \
    if (DO_AB) STAGE_B(((KT) + 1) * 64, (RBUF) ^ 1);                          \
    if (DO_AB) HCOMP(((KT) + 1) & 1, (RBUF) ^ 1);                             \
    if (DO_W1) {                                                              \
      if (t < 128) GLDS16(w1 + (size_t)((KT) + 2) * 512 + c4,                 \
                          (float*)w1s[(KT) & 1] + t * 4);                     \
      b1a = *(const f32x4*)(b1 + ((KT) + 2) * 64 + lc * 8);                   \
      b1b = *(const f32x4*)(b1 + ((KT) + 2) * 64 + lc * 8 + 4);               \
    }                                                                         \
    bf16x8 af0[4], af1[4], bfx0[3], bfx1[3];                                  \
    _Pragma("unroll") for (int mi = 0; mi < 4; ++mi) {                        \
      af0[mi] = *(const bf16x8*)(la + offA0 + mi * 1024);                     \
      af1[mi] = *(const bf16x8*)(la + offA1 + mi * 1024);                     \
    }                                                                         \
    _Pragma("unroll") for (int ni = 0; ni < 3; ++ni) {                        \
      bfx0[ni] = *(const bf16x8*)(la + offB0 + ni * 1024);                    \
      bfx1[ni] = *(const bf16x8*)(la + offB1 + ni * 1024);                    \
    }                                                                         \
    __builtin_amdgcn_s_setprio(1);                                            \
    _Pragma("unroll") for (int mi = 0; mi < 4; ++mi)                          \
      _Pragma("unroll") for (int ni = 0; ni < 3; ++ni)                        \
        acc[mi][ni] = __builtin_amdgcn_mfma_f32_16x16x32_bf16(                \
            af0[mi], bfx0[ni], acc[mi][ni], 0, 0, 0);                         \
    _Pragma("unroll") for (int mi = 0; mi < 4; ++mi)                          \
      _Pragma("unroll") for (int ni = 0; ni < 3; ++ni)                        \
        acc[mi][ni] = __builtin_amdgcn_mfma_f32_16x16x32_bf16(                \
            af1[mi], bfx1[ni], acc[mi][ni], 0, 0, 0);                         \
    __builtin_amdgcn_s_setprio(0);                                            \
    bf16x8 ag0[4], ag1[4];                                                    \
    _Pragma("unroll") for (int mi = 0; mi < 4; ++mi) {                        \
      ag0[mi] = *(const bf16x8*)(la + offA0 + (mi + 4) * 1024);               \
      ag1[mi] = *(const bf16x8*)(la + offA1 + (mi + 4) * 1024);               \
    }                                                                         \
    __builtin_amdgcn_s_setprio(1);                                            \
    _Pragma("unroll") for (int mi = 0; mi < 4; ++mi)                          \
      _Pragma("unroll") for (int ni = 0; ni < 3; ++ni)                        \
        acc[mi + 4][ni] = __builtin_amdgcn_mfma_f32_16x16x32_bf16(            \
            ag0[mi], bfx0[ni], acc[mi + 4][ni], 0, 0, 0);                     \
    _Pragma("unroll") for (int mi = 0; mi < 4; ++mi)                          \
      _Pragma("unroll") for (int ni = 0; ni < 3; ++ni)                        \
        acc[mi + 4][ni] = __builtin_amdgcn_mfma_f32_16x16x32_bf16(            \
            ag1[mi], bfx1[ni], acc[mi + 4][ni], 0, 0, 0);                     \
    __builtin_amdgcn_s_setprio(0);                                            \
    asm volatile("s_waitcnt vmcnt(0) lgkmcnt(0)" ::: "memory");               \
    __builtin_amdgcn_s_barrier();                                             \
  }

  // main: 48 K-tiles of 64. Tile KT consumes buf[KT&1]; produces A(KT+1)
  // (using w1s[(KT+1)&1], staged 2 tiles earlier) and stages B(KT+1);
  // stages w1(KT+2) into w1s[KT&1] and reg-loads b1(KT+2).
#pragma unroll 1
  for (int tt = 0; tt < 46; tt += 2) {
    TILE(tt + 0, 0, 1, 1);
    TILE(tt + 1, 1, 1, 1);
  }
  TILE(46, 0, 1, 0);
  TILE(47, 1, 0, 0);

#undef TILE
#undef STAGE_B
#undef HCOMP

  // epilogue: C/D layout col = l&15, row = (l>>4)*4 + r
#pragma unroll
  for (int mi = 0; mi < 8; ++mi) {
    const size_t row = m0 + wr * 128 + mi * 16 + lk * 4;
#pragma unroll
    for (int ni = 0; ni < 3; ++ni) {
      const int col = n0 + wc * 48 + ni * 16 + lr;
      const float bias = b2[col];
#pragma unroll
      for (int rr = 0; rr < 4; ++rr) {
        C[(row + rr) * N + col] = acc[mi][ni][rr] + bias;
      }
    }
  }
}

// ---------------- fallback: correct fp32 path if workspace too small --------
__global__ __launch_bounds__(256) void fallback_fused(const float* __restrict__ x,
                                                      const float* __restrict__ phi,
                                                      const float* __restrict__ w1,
                                                      const float* __restrict__ b1,
                                                      const float* __restrict__ w2,
                                                      const float* __restrict__ b2,
                                                      float* __restrict__ out) {
  __shared__ float s_h[FF_DIM];
  __shared__ float s_meas[Q_N];
  const int t = threadIdx.x;
  const size_t m = blockIdx.x;
  if (t < Q_N) s_meas[t] = __cosf(x[m * E_DIM + t] + phi[t]);
  __syncthreads();
  for (int f = t; f < FF_DIM; f += 256) {
    const float4* wr = (const float4*)(w1 + (size_t)f * Q_N);
    float4 a = wr[0], b = wr[1];
    float acc = b1[f];
    acc = fmaf(s_meas[0], a.x, acc); acc = fmaf(s_meas[1], a.y, acc);
    acc = fmaf(s_meas[2], a.z, acc); acc = fmaf(s_meas[3], a.w, acc);
    acc = fmaf(s_meas[4], b.x, acc); acc = fmaf(s_meas[5], b.y, acc);
    acc = fmaf(s_meas[6], b.z, acc); acc = fmaf(s_meas[7], b.w, acc);
    s_h[f] = fmaxf(acc, 0.f);
  }
  __syncthreads();
  for (int e = t; e < E_DIM; e += 256) {
    const float* w2r = w2 + (size_t)e * FF_DIM;
    float acc = b2[e];
    for (int f = 0; f < FF_DIM; f += 4) {
      float4 wv = *(const float4*)(w2r + f);
      acc = fmaf(s_h[f + 0], wv.x, acc);
      acc = fmaf(s_h[f + 1], wv.y, acc);
      acc = fmaf(s_h[f + 2], wv.z, acc);
      acc = fmaf(s_h[f + 3], wv.w, acc);
    }
    out[m * E_DIM + e] = acc;
  }
}

extern "C" void kernel_launch(void* const* d_in, const int* in_sizes, int n_in,
                              void* d_out, int out_size, void* d_ws, size_t ws_size,
                              hipStream_t stream) {
  const float* x   = (const float*)d_in[0];
  const float* phi = (const float*)d_in[1];
  const float* w1  = (const float*)d_in[2];
  const float* b1  = (const float*)d_in[3];
  const float* w2  = (const float*)d_in[4];
  const float* b2  = (const float*)d_in[5];
  float* out = (float*)d_out;

  const size_t W2B_BYTES = (size_t)E_DIM * FF_DIM * 2;   // 4,718,592
  const size_t NEED = W2B_BYTES;

  if (ws_size >= NEED) {
    __hip_bfloat16* w2b = (__hip_bfloat16*)d_ws;
    cvt_w2<<<(E_DIM * FF_DIM) / (256 * 4), 256, 0, stream>>>(w2, w2b);
    // BM=256, BN=192 -> 64*4 = 256 workgroups (matches in-kernel swizzle)
    ffn_fused<<<(M_TOK / 256) * (E_DIM / 192), 512, 0, stream>>>(x, phi, w1, b1,
                                                                 w2b, b2, out);
  } else {
    fallback_fused<<<M_TOK, 256, 0, stream>>>(x, phi, w1, b1, w2, b2, out);
  }
}

// Round 4
// 105.381 us; speedup vs baseline: 1.3174x; 1.3174x over previous
//
#include <hip/hip_runtime.h>
#include <hip/hip_bf16.h>
#include <stdint.h>

// Problem constants
#define M_TOK 16384   // B*S = 8*2048
#define E_DIM 768
#define FF_DIM 3072
#define Q_N 8

typedef __attribute__((ext_vector_type(8))) short bf16x8;
typedef __attribute__((ext_vector_type(4))) float f32x4;

__device__ inline unsigned short f2bf(float f) {
  union { float f; unsigned u; } v; v.f = f;
  unsigned r = v.u + 0x7fffu + ((v.u >> 16) & 1u);  // round-to-nearest-even
  return (unsigned short)(r >> 16);
}

// ---------------- kernel 0: w2 fp32 -> bf16 ----------------
__global__ __launch_bounds__(256) void cvt_w2(const float* __restrict__ w2,
                                              __hip_bfloat16* __restrict__ w2b) {
  int i = (blockIdx.x * 256 + threadIdx.x) * 4;
  const int n = E_DIM * FF_DIM;
  if (i < n) {
    float4 v = *(const float4*)(w2 + i);
    ushort4 o;
    o.x = f2bf(v.x); o.y = f2bf(v.y); o.z = f2bf(v.z); o.w = f2bf(v.w);
    *(ushort4*)((unsigned short*)w2b + i) = o;
  }
}

// ---------------- kernel 1: h = relu(cos(x[:, :8]+phi) @ w1^T + b1), bf16 ----
__global__ __launch_bounds__(256) void compute_h(const float* __restrict__ x,
                                                 const float* __restrict__ phi,
                                                 const float* __restrict__ w1,
                                                 const float* __restrict__ b1,
                                                 __hip_bfloat16* __restrict__ hout) {
  __shared__ float s_meas[32][8];
  const int t = threadIdx.x;
  const int bm = blockIdx.x / 6;
  const int bf = blockIdx.x % 6;
  const int m0 = bm * 32;
  const int f0 = bf * 512;

  if (t < 64) {
    int m = t >> 1, hh = t & 1;
    float4 v = *(const float4*)(x + (size_t)(m0 + m) * E_DIM + hh * 4);
    float4 p = *(const float4*)(phi + hh * 4);
    s_meas[m][hh * 4 + 0] = __cosf(v.x + p.x);
    s_meas[m][hh * 4 + 1] = __cosf(v.y + p.y);
    s_meas[m][hh * 4 + 2] = __cosf(v.z + p.z);
    s_meas[m][hh * 4 + 3] = __cosf(v.w + p.w);
  }
  __syncthreads();

  const float4* wr = (const float4*)(w1 + (size_t)(f0 + 2 * t) * Q_N);
  float4 a0 = wr[0], a1 = wr[1], b0 = wr[2], b1v = wr[3];
  float wA[8] = {a0.x, a0.y, a0.z, a0.w, a1.x, a1.y, a1.z, a1.w};
  float wB[8] = {b0.x, b0.y, b0.z, b0.w, b1v.x, b1v.y, b1v.z, b1v.w};
  const float biasA = b1[f0 + 2 * t];
  const float biasB = b1[f0 + 2 * t + 1];

  uint32_t* dst32 = (uint32_t*)hout;
  for (int m = 0; m < 32; ++m) {
    float a = biasA, b = biasB;
#pragma unroll
    for (int q = 0; q < 8; ++q) {
      float mv = s_meas[m][q];
      a = fmaf(mv, wA[q], a);
      b = fmaf(mv, wB[q], b);
    }
    a = fmaxf(a, 0.f);
    b = fmaxf(b, 0.f);
    uint32_t pack = (uint32_t)f2bf(a) | ((uint32_t)f2bf(b) << 16);
    dst32[(size_t)(m0 + m) * (FF_DIM / 2) + (f0 / 2) + t] = pack;
  }
}

// ---------------- kernel 2: C[M,N] = h[M,K] @ w2b[N,K]^T + b2 ---------------
// R4: OCCUPANCY lever. BM=128, BN=192, BK=64 -> LDS/block = 2 x 40KB = 80KB
// -> EXACTLY 2 blocks/CU (160KB pool), grid 128x4 = 512 wgs = 2/CU, 16
// waves/CU. When one block drains vmcnt(0)+barrier, the OTHER block's waves
// issue MFMA (m114 inter-block overlap) — attacks the ~1700cyc/tile stall
// that within-block schedule edits (R1/R2) could not move.
// Body is R0's proven 1-barrier TILE verbatim, halved in M: per-wave 64x48,
// acc[4][3], 14 ds_read_b128 up-front, 24 MFMA, vmcnt(0), barrier.
// __launch_bounds__(512,4) caps VGPR at 128 for 4 waves/SIMD.
#define GLDS16(g, l)                                                          \
  __builtin_amdgcn_global_load_lds(                                           \
      (const __attribute__((address_space(1))) void*)(g),                     \
      (__attribute__((address_space(3))) void*)(l), 16, 0, 0)

#define BUF_ELEMS 20480   // (128*64 + 192*64) bf16 elems = 40KB
#define B_OFF 8192        // A region: 128*64 elems

__global__ __launch_bounds__(512, 4) void gemm_bt(const __hip_bfloat16* __restrict__ A,
                                                  const __hip_bfloat16* __restrict__ Bw,
                                                  const float* __restrict__ b2,
                                                  float* __restrict__ C) {
  const int K = FF_DIM;   // 3072
  const int N = E_DIM;    // 768

  __shared__ __align__(16) __hip_bfloat16 lds[2 * BUF_ELEMS];  // 80 KiB exact

  const int t = threadIdx.x;
  // XCD-aware bijective swizzle: nwg = 512, 512 % 8 == 0
  const int swz = (blockIdx.x & 7) * 64 + (blockIdx.x >> 3);
  const int bm = swz >> 2;        // 0..127
  const int bn = swz & 3;         // 0..3
  const size_t m0 = (size_t)bm * 128;
  const int n0 = bn * 192;

  const int w = t >> 6, l = t & 63;
  const int wr = w >> 2;          // 0..1  (M wave row)
  const int wc = w & 3;           // 0..3  (N wave col)
  const int lr = l & 15;
  const int lk = l >> 4;          // 0..3

  // fragment-read swizzled chunk constants: row&7 == lr&7 for all frag rows
  const int x0 = lk ^ (lr & 7);        // k-half 0 chunk
  const int x1 = x0 ^ 4;               // k-half 1 chunk
  const int baseA = (wr * 64 + lr) * 64;
  const int baseB = B_OFF + (wc * 48 + lr) * 64;
  const int offA0 = baseA + x0 * 8, offA1 = baseA + x1 * 8;
  const int offB0 = baseB + x0 * 8, offB1 = baseB + x1 * 8;

  // staging: span = 64 rows x 128B = 8KB = 512 thr x 16B. dest = t*16B (linear).
  // row-in-span rs = t>>3, phys chunk pc = t&7, logical chunk lc = pc ^ (rs&7).
  const int rs = t >> 3;
  const int lc = (t & 7) ^ (rs & 7);
  const __hip_bfloat16* sA[2];
  const __hip_bfloat16* sB[3];
#pragma unroll
  for (int s = 0; s < 2; ++s) sA[s] = A + (m0 + s * 64 + rs) * (size_t)K + lc * 8;
#pragma unroll
  for (int s = 0; s < 3; ++s) sB[s] = Bw + ((size_t)n0 + s * 64 + rs) * K + lc * 8;

  f32x4 acc[4][3] = {};

#define STAGE(K0S, WBUF)                                                      \
  {                                                                           \
    __hip_bfloat16* ld = lds + (WBUF) * BUF_ELEMS + t * 8;                    \
    GLDS16(sA[0] + (K0S), ld);                                                \
    GLDS16(sA[1] + (K0S), ld + 4096);                                         \
    GLDS16(sB[0] + (K0S), ld + 8192);                                         \
    GLDS16(sB[1] + (K0S), ld + 12288);                                        \
    GLDS16(sB[2] + (K0S), ld + 16384);                                        \
  }

#define TILE(KT, RBUF, DO_STAGE)                                              \
  {                                                                           \
    if (DO_STAGE) STAGE(((KT) + 1) * 64, (RBUF) ^ 1);                         \
    const __hip_bfloat16* la = lds + (RBUF) * BUF_ELEMS;                      \
    bf16x8 af0[4], bfx0[3], af1[4], bfx1[3];                                  \
    /* all 14 reads up-front, distinct regs -> counted lgkm overlap */        \
    _Pragma("unroll") for (int mi = 0; mi < 4; ++mi)                          \
        af0[mi] = *(const bf16x8*)(la + offA0 + mi * 1024);                   \
    _Pragma("unroll") for (int ni = 0; ni < 3; ++ni)                          \
        bfx0[ni] = *(const bf16x8*)(la + offB0 + ni * 1024);                  \
    _Pragma("unroll") for (int mi = 0; mi < 4; ++mi)                          \
        af1[mi] = *(const bf16x8*)(la + offA1 + mi * 1024);                   \
    _Pragma("unroll") for (int ni = 0; ni < 3; ++ni)                          \
        bfx1[ni] = *(const bf16x8*)(la + offB1 + ni * 1024);                  \
    __builtin_amdgcn_s_setprio(1);                                            \
    _Pragma("unroll") for (int mi = 0; mi < 4; ++mi)                          \
        _Pragma("unroll") for (int ni = 0; ni < 3; ++ni)                      \
            acc[mi][ni] = __builtin_amdgcn_mfma_f32_16x16x32_bf16(            \
                af0[mi], bfx0[ni], acc[mi][ni], 0, 0, 0);                     \
    _Pragma("unroll") for (int mi = 0; mi < 4; ++mi)                          \
        _Pragma("unroll") for (int ni = 0; ni < 3; ++ni)                      \
            acc[mi][ni] = __builtin_amdgcn_mfma_f32_16x16x32_bf16(            \
                af1[mi], bfx1[ni], acc[mi][ni], 0, 0, 0);                     \
    __builtin_amdgcn_s_setprio(0);                                            \
    asm volatile("s_waitcnt vmcnt(0)" ::: "memory");                          \
    __builtin_amdgcn_s_barrier();                                             \
  }

  // prologue: stage tile 0 into buf 0
  STAGE(0, 0);
  asm volatile("s_waitcnt vmcnt(0)" ::: "memory");
  __builtin_amdgcn_s_barrier();

  // main: 48 K-tiles of 64, two per iteration (static buffers)
#pragma unroll 1
  for (int tt = 0; tt < 46; tt += 2) {
    TILE(tt + 0, 0, 1);
    TILE(tt + 1, 1, 1);
  }
  TILE(46, 0, 1);
  TILE(47, 1, 0);

#undef TILE
#undef STAGE

  // epilogue: C/D layout col = l&15, row = (l>>4)*4 + r
#pragma unroll
  for (int mi = 0; mi < 4; ++mi) {
    const size_t row = m0 + wr * 64 + mi * 16 + lk * 4;
#pragma unroll
    for (int ni = 0; ni < 3; ++ni) {
      const int col = n0 + wc * 48 + ni * 16 + lr;
      const float bias = b2[col];
#pragma unroll
      for (int rr = 0; rr < 4; ++rr) {
        C[(row + rr) * N + col] = acc[mi][ni][rr] + bias;
      }
    }
  }
}

// ---------------- fallback: correct fp32 path if workspace too small --------
__global__ __launch_bounds__(256) void fallback_fused(const float* __restrict__ x,
                                                      const float* __restrict__ phi,
                                                      const float* __restrict__ w1,
                                                      const float* __restrict__ b1,
                                                      const float* __restrict__ w2,
                                                      const float* __restrict__ b2,
                                                      float* __restrict__ out) {
  __shared__ float s_h[FF_DIM];
  __shared__ float s_meas[Q_N];
  const int t = threadIdx.x;
  const size_t m = blockIdx.x;
  if (t < Q_N) s_meas[t] = __cosf(x[m * E_DIM + t] + phi[t]);
  __syncthreads();
  for (int f = t; f < FF_DIM; f += 256) {
    const float4* wr = (const float4*)(w1 + (size_t)f * Q_N);
    float4 a = wr[0], b = wr[1];
    float acc = b1[f];
    acc = fmaf(s_meas[0], a.x, acc); acc = fmaf(s_meas[1], a.y, acc);
    acc = fmaf(s_meas[2], a.z, acc); acc = fmaf(s_meas[3], a.w, acc);
    acc = fmaf(s_meas[4], b.x, acc); acc = fmaf(s_meas[5], b.y, acc);
    acc = fmaf(s_meas[6], b.z, acc); acc = fmaf(s_meas[7], b.w, acc);
    s_h[f] = fmaxf(acc, 0.f);
  }
  __syncthreads();
  for (int e = t; e < E_DIM; e += 256) {
    const float* w2r = w2 + (size_t)e * FF_DIM;
    float acc = b2[e];
    for (int f = 0; f < FF_DIM; f += 4) {
      float4 wv = *(const float4*)(w2r + f);
      acc = fmaf(s_h[f + 0], wv.x, acc);
      acc = fmaf(s_h[f + 1], wv.y, acc);
      acc = fmaf(s_h[f + 2], wv.z, acc);
      acc = fmaf(s_h[f + 3], wv.w, acc);
    }
    out[m * E_DIM + e] = acc;
  }
}

extern "C" void kernel_launch(void* const* d_in, const int* in_sizes, int n_in,
                              void* d_out, int out_size, void* d_ws, size_t ws_size,
                              hipStream_t stream) {
  const float* x   = (const float*)d_in[0];
  const float* phi = (const float*)d_in[1];
  const float* w1  = (const float*)d_in[2];
  const float* b1  = (const float*)d_in[3];
  const float* w2  = (const float*)d_in[4];
  const float* b2  = (const float*)d_in[5];
  float* out = (float*)d_out;

  const size_t H_BYTES   = (size_t)M_TOK * FF_DIM * 2;   // 100,663,296
  const size_t W2B_BYTES = (size_t)E_DIM * FF_DIM * 2;   // 4,718,592
  const size_t NEED = H_BYTES + W2B_BYTES;

  if (ws_size >= NEED) {
    __hip_bfloat16* h   = (__hip_bfloat16*)d_ws;
    __hip_bfloat16* w2b = (__hip_bfloat16*)((char*)d_ws + H_BYTES);
    cvt_w2<<<(E_DIM * FF_DIM) / (256 * 4), 256, 0, stream>>>(w2, w2b);
    compute_h<<<(M_TOK / 32) * (FF_DIM / 512), 256, 0, stream>>>(x, phi, w1, b1, h);
    // BM=128, BN=192 -> 128*4 = 512 workgroups (matches in-kernel swizzle)
    gemm_bt<<<(M_TOK / 128) * (E_DIM / 192), 512, 0, stream>>>(h, w2b, b2, out);
  } else {
    fallback_fused<<<M_TOK, 256, 0, stream>>>(x, phi, w1, b1, w2, b2, out);
  }
}

// Round 5
// 98.416 us; speedup vs baseline: 1.4107x; 1.0708x over previous
//
#include <hip/hip_runtime.h>
#include <hip/hip_bf16.h>
#include <stdint.h>

// Problem constants
#define M_TOK 16384   // B*S = 8*2048
#define E_DIM 768
#define FF_DIM 3072
#define Q_N 8

typedef __attribute__((ext_vector_type(8))) short bf16x8;
typedef __attribute__((ext_vector_type(4))) float f32x4;

__device__ inline unsigned short f2bf(float f) {
  union { float f; unsigned u; } v; v.f = f;
  unsigned r = v.u + 0x7fffu + ((v.u >> 16) & 1u);  // round-to-nearest-even
  return (unsigned short)(r >> 16);
}

// ---------------- kernel 0: w2 fp32 -> bf16 ----------------
__global__ __launch_bounds__(256) void cvt_w2(const float* __restrict__ w2,
                                              __hip_bfloat16* __restrict__ w2b) {
  int i = (blockIdx.x * 256 + threadIdx.x) * 4;
  const int n = E_DIM * FF_DIM;
  if (i < n) {
    float4 v = *(const float4*)(w2 + i);
    ushort4 o;
    o.x = f2bf(v.x); o.y = f2bf(v.y); o.z = f2bf(v.z); o.w = f2bf(v.w);
    *(ushort4*)((unsigned short*)w2b + i) = o;
  }
}

// ---------------- kernel 1: h = relu(cos(x[:, :8]+phi) @ w1^T + b1), bf16 ----
__global__ __launch_bounds__(256) void compute_h(const float* __restrict__ x,
                                                 const float* __restrict__ phi,
                                                 const float* __restrict__ w1,
                                                 const float* __restrict__ b1,
                                                 __hip_bfloat16* __restrict__ hout) {
  __shared__ float s_meas[32][8];
  const int t = threadIdx.x;
  const int bm = blockIdx.x / 6;
  const int bf = blockIdx.x % 6;
  const int m0 = bm * 32;
  const int f0 = bf * 512;

  if (t < 64) {
    int m = t >> 1, hh = t & 1;
    float4 v = *(const float4*)(x + (size_t)(m0 + m) * E_DIM + hh * 4);
    float4 p = *(const float4*)(phi + hh * 4);
    s_meas[m][hh * 4 + 0] = __cosf(v.x + p.x);
    s_meas[m][hh * 4 + 1] = __cosf(v.y + p.y);
    s_meas[m][hh * 4 + 2] = __cosf(v.z + p.z);
    s_meas[m][hh * 4 + 3] = __cosf(v.w + p.w);
  }
  __syncthreads();

  const float4* wr = (const float4*)(w1 + (size_t)(f0 + 2 * t) * Q_N);
  float4 a0 = wr[0], a1 = wr[1], b0 = wr[2], b1v = wr[3];
  float wA[8] = {a0.x, a0.y, a0.z, a0.w, a1.x, a1.y, a1.z, a1.w};
  float wB[8] = {b0.x, b0.y, b0.z, b0.w, b1v.x, b1v.y, b1v.z, b1v.w};
  const float biasA = b1[f0 + 2 * t];
  const float biasB = b1[f0 + 2 * t + 1];

  uint32_t* dst32 = (uint32_t*)hout;
  for (int m = 0; m < 32; ++m) {
    float a = biasA, b = biasB;
#pragma unroll
    for (int q = 0; q < 8; ++q) {
      float mv = s_meas[m][q];
      a = fmaf(mv, wA[q], a);
      b = fmaf(mv, wB[q], b);
    }
    a = fmaxf(a, 0.f);
    b = fmaxf(b, 0.f);
    uint32_t pack = (uint32_t)f2bf(a) | ((uint32_t)f2bf(b) << 16);
    dst32[(size_t)(m0 + m) * (FF_DIM / 2) + (f0 / 2) + t] = pack;
  }
}

// ---------------- kernel 2: C[M,N] = h[M,K] @ w2b[N,K]^T + b2 ---------------
// R5: LDS-TRAFFIC lever. R4's model fit showed the kernel is LDS-read-bound
// (ds_read_b128 ~85 B/cyc/CU; per-tile read bytes ≈ observed cycles). LDS
// bytes/FLOP = 1/Mw + 1/Nw (wave-tile shape only). R0: 128x48 (0.0286),
// R4: 64x48 x2blk (0.0365 + shared pipe). R5: WAVE TILE 64x96 (0.026):
// BM=256, BN=192, BK=64, grid 64x4=256 (R0 geometry, staging/swizzle/
// 1-barrier loop IDENTICAL to R0); waves 4(M) x 2(N), acc[4][6],
// 20 ds_read_b128 -> 48 MFMA per thread-tile. Per-CU-tile: reads 160KB
// (~1880cyc) + writes 56KB vs MFMA 1550cyc -> near-balanced.
// Frags per k-half in separate scopes: live VGPR ~ 96 acc + 40 frag.
#define GLDS16(g, l)                                                          \
  __builtin_amdgcn_global_load_lds(                                           \
      (const __attribute__((address_space(1))) void*)(g),                     \
      (__attribute__((address_space(3))) void*)(l), 16, 0, 0)

#define BUF_ELEMS 28672   // (256*64 + 192*64) bf16 elems = 56KB
#define B_OFF 16384       // A region: 256*64 elems

__global__ __launch_bounds__(512, 1) void gemm_bt(const __hip_bfloat16* __restrict__ A,
                                                  const __hip_bfloat16* __restrict__ Bw,
                                                  const float* __restrict__ b2,
                                                  float* __restrict__ C) {
  const int K = FF_DIM;   // 3072
  const int N = E_DIM;    // 768

  __shared__ __align__(16) __hip_bfloat16 lds[2 * BUF_ELEMS];  // 112 KiB

  const int t = threadIdx.x;
  // XCD-aware bijective swizzle: nwg = 256, 256 % 8 == 0
  const int swz = (blockIdx.x & 7) * 32 + (blockIdx.x >> 3);
  const int bm = swz >> 2;        // 0..63
  const int bn = swz & 3;         // 0..3
  const size_t m0 = (size_t)bm * 256;
  const int n0 = bn * 192;

  const int w = t >> 6, l = t & 63;
  const int wr = w >> 1;          // 0..3  (M wave row, 64 rows each)
  const int wc = w & 1;           // 0..1  (N wave col, 96 cols each)
  const int lr = l & 15;
  const int lk = l >> 4;          // 0..3

  // fragment-read swizzled chunk constants: row&7 == lr&7 for all frag rows
  const int x0 = lk ^ (lr & 7);        // k-half 0 chunk
  const int x1 = x0 ^ 4;               // k-half 1 chunk
  const int baseA = (wr * 64 + lr) * 64;
  const int baseB = B_OFF + (wc * 96 + lr) * 64;
  const int offA0 = baseA + x0 * 8, offA1 = baseA + x1 * 8;
  const int offB0 = baseB + x0 * 8, offB1 = baseB + x1 * 8;

  // staging: span = 64 rows x 128B = 8KB = 512 thr x 16B. dest = t*16B (linear).
  // row-in-span rs = t>>3, phys chunk pc = t&7, logical chunk lc = pc ^ (rs&7).
  const int rs = t >> 3;
  const int lc = (t & 7) ^ (rs & 7);
  const __hip_bfloat16* sA[4];
  const __hip_bfloat16* sB[3];
#pragma unroll
  for (int s = 0; s < 4; ++s) sA[s] = A + (m0 + s * 64 + rs) * (size_t)K + lc * 8;
#pragma unroll
  for (int s = 0; s < 3; ++s) sB[s] = Bw + ((size_t)n0 + s * 64 + rs) * K + lc * 8;

  f32x4 acc[4][6] = {};

#define STAGE(K0S, WBUF)                                                      \
  {                                                                           \
    __hip_bfloat16* ld = lds + (WBUF) * BUF_ELEMS + t * 8;                    \
    GLDS16(sA[0] + (K0S), ld);                                                \
    GLDS16(sA[1] + (K0S), ld + 4096);                                         \
    GLDS16(sA[2] + (K0S), ld + 8192);                                         \
    GLDS16(sA[3] + (K0S), ld + 12288);                                        \
    GLDS16(sB[0] + (K0S), ld + 16384);                                        \
    GLDS16(sB[1] + (K0S), ld + 20480);                                        \
    GLDS16(sB[2] + (K0S), ld + 24576);                                        \
  }

#define TILE(KT, RBUF, DO_STAGE)                                              \
  {                                                                           \
    if (DO_STAGE) STAGE(((KT) + 1) * 64, (RBUF) ^ 1);                         \
    const __hip_bfloat16* la = lds + (RBUF) * BUF_ELEMS;                      \
    { /* ---- k-half 0 ---- */                                                \
      bf16x8 fa[4], fb[6];                                                    \
      _Pragma("unroll") for (int mi = 0; mi < 4; ++mi)                        \
          fa[mi] = *(const bf16x8*)(la + offA0 + mi * 1024);                  \
      _Pragma("unroll") for (int ni = 0; ni < 6; ++ni)                        \
          fb[ni] = *(const bf16x8*)(la + offB0 + ni * 1024);                  \
      __builtin_amdgcn_s_setprio(1);                                          \
      _Pragma("unroll") for (int mi = 0; mi < 4; ++mi)                        \
          _Pragma("unroll") for (int ni = 0; ni < 6; ++ni)                    \
              acc[mi][ni] = __builtin_amdgcn_mfma_f32_16x16x32_bf16(          \
                  fa[mi], fb[ni], acc[mi][ni], 0, 0, 0);                      \
      __builtin_amdgcn_s_setprio(0);                                          \
    }                                                                         \
    { /* ---- k-half 1 ---- */                                                \
      bf16x8 fa[4], fb[6];                                                    \
      _Pragma("unroll") for (int mi = 0; mi < 4; ++mi)                        \
          fa[mi] = *(const bf16x8*)(la + offA1 + mi * 1024);                  \
      _Pragma("unroll") for (int ni = 0; ni < 6; ++ni)                        \
          fb[ni] = *(const bf16x8*)(la + offB1 + ni * 1024);                  \
      __builtin_amdgcn_s_setprio(1);                                          \
      _Pragma("unroll") for (int mi = 0; mi < 4; ++mi)                        \
          _Pragma("unroll") for (int ni = 0; ni < 6; ++ni)                    \
              acc[mi][ni] = __builtin_amdgcn_mfma_f32_16x16x32_bf16(          \
                  fa[mi], fb[ni], acc[mi][ni], 0, 0, 0);                      \
      __builtin_amdgcn_s_setprio(0);                                          \
    }                                                                         \
    asm volatile("s_waitcnt vmcnt(0)" ::: "memory");                          \
    __builtin_amdgcn_s_barrier();                                             \
  }

  // prologue: stage tile 0 into buf 0
  STAGE(0, 0);
  asm volatile("s_waitcnt vmcnt(0)" ::: "memory");
  __builtin_amdgcn_s_barrier();

  // main: 48 K-tiles of 64, two per iteration (static buffers)
#pragma unroll 1
  for (int tt = 0; tt < 46; tt += 2) {
    TILE(tt + 0, 0, 1);
    TILE(tt + 1, 1, 1);
  }
  TILE(46, 0, 1);
  TILE(47, 1, 0);

#undef TILE
#undef STAGE

  // epilogue: C/D layout col = l&15, row = (l>>4)*4 + r
#pragma unroll
  for (int mi = 0; mi < 4; ++mi) {
    const size_t row = m0 + wr * 64 + mi * 16 + lk * 4;
#pragma unroll
    for (int ni = 0; ni < 6; ++ni) {
      const int col = n0 + wc * 96 + ni * 16 + lr;
      const float bias = b2[col];
#pragma unroll
      for (int rr = 0; rr < 4; ++rr) {
        C[(row + rr) * N + col] = acc[mi][ni][rr] + bias;
      }
    }
  }
}

// ---------------- fallback: correct fp32 path if workspace too small --------
__global__ __launch_bounds__(256) void fallback_fused(const float* __restrict__ x,
                                                      const float* __restrict__ phi,
                                                      const float* __restrict__ w1,
                                                      const float* __restrict__ b1,
                                                      const float* __restrict__ w2,
                                                      const float* __restrict__ b2,
                                                      float* __restrict__ out) {
  __shared__ float s_h[FF_DIM];
  __shared__ float s_meas[Q_N];
  const int t = threadIdx.x;
  const size_t m = blockIdx.x;
  if (t < Q_N) s_meas[t] = __cosf(x[m * E_DIM + t] + phi[t]);
  __syncthreads();
  for (int f = t; f < FF_DIM; f += 256) {
    const float4* wr = (const float4*)(w1 + (size_t)f * Q_N);
    float4 a = wr[0], b = wr[1];
    float acc = b1[f];
    acc = fmaf(s_meas[0], a.x, acc); acc = fmaf(s_meas[1], a.y, acc);
    acc = fmaf(s_meas[2], a.z, acc); acc = fmaf(s_meas[3], a.w, acc);
    acc = fmaf(s_meas[4], b.x, acc); acc = fmaf(s_meas[5], b.y, acc);
    acc = fmaf(s_meas[6], b.z, acc); acc = fmaf(s_meas[7], b.w, acc);
    s_h[f] = fmaxf(acc, 0.f);
  }
  __syncthreads();
  for (int e = t; e < E_DIM; e += 256) {
    const float* w2r = w2 + (size_t)e * FF_DIM;
    float acc = b2[e];
    for (int f = 0; f < FF_DIM; f += 4) {
      float4 wv = *(const float4*)(w2r + f);
      acc = fmaf(s_h[f + 0], wv.x, acc);
      acc = fmaf(s_h[f + 1], wv.y, acc);
      acc = fmaf(s_h[f + 2], wv.z, acc);
      acc = fmaf(s_h[f + 3], wv.w, acc);
    }
    out[m * E_DIM + e] = acc;
  }
}

extern "C" void kernel_launch(void* const* d_in, const int* in_sizes, int n_in,
                              void* d_out, int out_size, void* d_ws, size_t ws_size,
                              hipStream_t stream) {
  const float* x   = (const float*)d_in[0];
  const float* phi = (const float*)d_in[1];
  const float* w1  = (const float*)d_in[2];
  const float* b1  = (const float*)d_in[3];
  const float* w2  = (const float*)d_in[4];
  const float* b2  = (const float*)d_in[5];
  float* out = (float*)d_out;

  const size_t H_BYTES   = (size_t)M_TOK * FF_DIM * 2;   // 100,663,296
  const size_t W2B_BYTES = (size_t)E_DIM * FF_DIM * 2;   // 4,718,592
  const size_t NEED = H_BYTES + W2B_BYTES;

  if (ws_size >= NEED) {
    __hip_bfloat16* h   = (__hip_bfloat16*)d_ws;
    __hip_bfloat16* w2b = (__hip_bfloat16*)((char*)d_ws + H_BYTES);
    cvt_w2<<<(E_DIM * FF_DIM) / (256 * 4), 256, 0, stream>>>(w2, w2b);
    compute_h<<<(M_TOK / 32) * (FF_DIM / 512), 256, 0, stream>>>(x, phi, w1, b1, h);
    // BM=256, BN=192 -> 64*4 = 256 workgroups (matches in-kernel swizzle)
    gemm_bt<<<(M_TOK / 256) * (E_DIM / 192), 512, 0, stream>>>(h, w2b, b2, out);
  } else {
    fallback_fused<<<M_TOK, 256, 0, stream>>>(x, phi, w1, b1, w2, b2, out);
  }
}